// Round 3
// baseline (95.005 us; speedup 1.0000x reference)
//
#include <hip/hip_runtime.h>

// y[b,co,h,w] = sum_{ci,kk} x[b,ci,h,w+kk-1] * wt[co,ci,kk]; roll(+1,H) folded into
// the store: computed row h lands at hout=(h+1)%28.
// GEMM: C[32 x 32pad] = W[32 x 384] * im2col(x); K order k = kk*128 + ci.
// mfma_f32_32x32x16_bf16; C/D: col=lane&31, row=(reg&3)+8*(reg>>2)+4*(lane>>5).

#define CIN   128
#define COUT  32
#define HH    28
#define WW    28
#define CIP   136   // ci padded 128->136: stride 272B -> optimal 8-bank-start b128 pattern
#define WPD   34    // wp = w+1 in [0,33]; wp=0 and wp>=29 are zero halo
#define HROWS 2
#define NTHR  128

typedef __attribute__((ext_vector_type(8))) short short8;
typedef __attribute__((ext_vector_type(8))) __bf16 bf16x8;
typedef __attribute__((ext_vector_type(16))) float f32x16;

__device__ inline unsigned short f2bf(float f) {
    union { float f; unsigned u; } v; v.f = f;
    return (unsigned short)((v.u + 0x7FFFu + ((v.u >> 16) & 1u)) >> 16);  // RNE
}

// ---- weights -> A-fragment layout wf[s][lane][j], s=0..23 ----
__global__ void build_wfrag(const float* __restrict__ wt, unsigned short* __restrict__ wf) {
    int t = blockIdx.x * 256 + threadIdx.x;            // 24*64*8 = 12288
    if (t >= 24 * 64 * 8) return;
    int j = t & 7, lane = (t >> 3) & 63, s = t >> 9;
    int co = lane & 31;
    int k  = s * 16 + (lane >> 5) * 8 + j;
    int kk = k >> 7, ci = k & 127;
    wf[t] = f2bf(wt[((size_t)co * CIN + ci) * 3 + kk]);
}

// ---- main: block = 128 thr = 2 waves = 2 h-rows of one b; grid 14 x 128 = 1792 ----
__global__ __launch_bounds__(NTHR, 4) void conv_mfma(
    const float* __restrict__ x,
    const unsigned short* __restrict__ wf,
    float* __restrict__ out)
{
    __shared__ __align__(16) unsigned short xt[HROWS][WPD][CIP];   // 18,496 B

    const int tid = threadIdx.x;
    const int hp  = blockIdx.x;           // 0..13
    const int b   = blockIdx.y;           // 0..127
    const int h0  = hp * HROWS;
    const float* xb = x + (size_t)b * CIN * HH * WW;

    // zero W-halo columns (wp=0 and wp=29..33) with u32 writes
    {
        unsigned int* xu = (unsigned int*)xt;
        const int ROWU = CIP / 2;          // 68 u32 per wp-row
        const int HU   = WPD * ROWU;       // u32 per h-slab
        for (int i = tid; i < HROWS * 6 * ROWU; i += NTHR) {
            int hl  = i / (6 * ROWU);
            int r   = i - hl * (6 * ROWU);
            int off = (r < ROWU) ? r : (29 * ROWU + (r - ROWU));
            xu[hl * HU + off] = 0u;
        }
    }

    // stage x[b, ci, h0+hl, :] -> xt[hl][1+w][ci]  (fp32->bf16 transpose)
#pragma unroll 2
    for (int it = 0; it < 14; ++it) {
        int idx  = tid + it * NTHR;       // float4 index over 128ci * 2h * 7
        int w4   = idx % 7;
        int rest = idx / 7;
        int hl   = rest & (HROWS - 1);
        int ci   = rest >> 1;
        float4 v = *(const float4*)(xb + ((size_t)ci * HH + (h0 + hl)) * WW + w4 * 4);
        int wp = 1 + w4 * 4;
        xt[hl][wp + 0][ci] = f2bf(v.x);
        xt[hl][wp + 1][ci] = f2bf(v.y);
        xt[hl][wp + 2][ci] = f2bf(v.z);
        xt[hl][wp + 3][ci] = f2bf(v.w);
    }

    __syncthreads();

    const int lane = tid & 63;
    const int hl   = tid >> 6;            // wave id = local h row
    const int n    = lane & 31;           // output w (valid < 28)
    const int half = lane >> 5;
    f32x16 acc = {0,0,0,0,0,0,0,0,0,0,0,0,0,0,0,0};

    // K-loop: 3 batches (= kernel tap kk) of 8 MFMA steps; only 8 afr live at a time
#pragma unroll
    for (int kk = 0; kk < 3; ++kk) {
        short8 afr[8];
#pragma unroll
        for (int u = 0; u < 8; ++u)
            afr[u] = *(const short8*)(wf + (size_t)((kk * 8 + u) * 64 + lane) * 8);
#pragma unroll
        for (int u = 0; u < 8; ++u) {
            short8 bfr = *(const short8*)&xt[hl][n + kk][u * 16 + half * 8];
            acc = __builtin_amdgcn_mfma_f32_32x32x16_bf16(
                __builtin_bit_cast(bf16x8, afr[u]),
                __builtin_bit_cast(bf16x8, bfr), acc, 0, 0, 0);
        }
    }

    // epilogue: roll(+1); pad columns n>=28 dropped
    if (n < WW) {
        const int hout = (h0 + hl + 1) % HH;
#pragma unroll
        for (int r = 0; r < 16; ++r) {
            int co = (r & 3) + 8 * (r >> 2) + 4 * half;
            out[(((size_t)b * COUT + co) * HH + hout) * WW + n] = acc[r];
        }
    }
}

extern "C" void kernel_launch(void* const* d_in, const int* in_sizes, int n_in,
                              void* d_out, int out_size, void* d_ws, size_t ws_size,
                              hipStream_t stream) {
    const float* x  = (const float*)d_in[0];
    const float* wt = (const float*)d_in[1];
    float* out = (float*)d_out;
    unsigned short* wf = (unsigned short*)d_ws;    // 24,576 B of scratch

    build_wfrag<<<48, 256, 0, stream>>>(wt, wf);
    dim3 grid(HH / HROWS, 128);                    // 14 x 128 = 1792 blocks, 7/CU
    conv_mfma<<<grid, NTHR, 0, stream>>>(x, wf, out);
}

// Round 4
// 94.234 us; speedup vs baseline: 1.0082x; 1.0082x over previous
//
#include <hip/hip_runtime.h>

// y[b,co,h,w] = sum_{ci,kk} x[b,ci,h,w+kk-1] * wt[co,ci,kk]; roll(+1,H) folded into
// the store: computed row h lands at hout=(h+1)%28.
// GEMM: C[32 x 32pad] = W[32 x 384] * im2col(x); K order k = kk*128 + ci.
// mfma_f32_32x32x16_bf16; C/D: col=lane&31, row=(reg&3)+8*(reg>>2)+4*(lane>>5).

#define CIN   128
#define COUT  32
#define HH    28
#define WW    28
#define CIP   136   // ci padded 128->136 (stride 272B): b128 reads hit all 32 banks (8-cyc optimal)
#define WPD   34    // wp = w+1; reads reach wp=33 (discarded cols) -> rows allocated, only 0 & 29 zeroed
#define HROWS 2
#define NTHR  128

typedef __attribute__((ext_vector_type(8))) short short8;
typedef __attribute__((ext_vector_type(8))) __bf16 bf16x8;
typedef __attribute__((ext_vector_type(16))) float f32x16;

__device__ inline unsigned short f2bf(float f) {
    union { float f; unsigned u; } v; v.f = f;
    return (unsigned short)((v.u + 0x7FFFu + ((v.u >> 16) & 1u)) >> 16);  // RNE
}

// pack two f32 -> packed bf16x2 (low = a, high = b)
__device__ inline unsigned int pack_bf2(float a, float b) {
#if __has_builtin(__builtin_amdgcn_cvt_pk_bf16_f32)
    typedef __attribute__((ext_vector_type(2))) __bf16 bf16x2;
    bf16x2 t = __builtin_amdgcn_cvt_pk_bf16_f32(a, b);
    return __builtin_bit_cast(unsigned int, t);
#else
    return (unsigned)f2bf(a) | ((unsigned)f2bf(b) << 16);
#endif
}

// ---- weights -> A-fragment layout wf[s][lane][j], s=0..23 ----
__global__ void build_wfrag(const float* __restrict__ wt, unsigned short* __restrict__ wf) {
    int t = blockIdx.x * 256 + threadIdx.x;            // 24*64*8 = 12288
    if (t >= 24 * 64 * 8) return;
    int j = t & 7, lane = (t >> 3) & 63, s = t >> 9;
    int co = lane & 31;
    int k  = s * 16 + (lane >> 5) * 8 + j;
    int kk = k >> 7, ci = k & 127;
    wf[t] = f2bf(wt[((size_t)co * CIN + ci) * 3 + kk]);
}

// ---- main: block = 128 thr = 2 waves = 2 h-rows of one b; grid 14 x 128 = 1792 ----
__global__ __launch_bounds__(NTHR, 3) void conv_mfma(
    const float* __restrict__ x,
    const unsigned short* __restrict__ wf,
    float* __restrict__ out)
{
    __shared__ __align__(16) unsigned short xt[HROWS][WPD][CIP];   // 18,496 B

    const int tid = threadIdx.x;
    const int hp  = blockIdx.x;           // 0..13
    const int b   = blockIdx.y;           // 0..127
    const int h0  = hp * HROWS;
    const float* xb = x + (size_t)b * CIN * HH * WW;

    // zero only consumed halo rows: wp=0 (kk=0 left edge) and wp=29 (kk=2 right edge)
    {
        unsigned int* xu = (unsigned int*)xt;
        const int ROWU = CIP / 2;          // 68 u32 per wp-row
        for (int i = tid; i < 4 * ROWU; i += NTHR) {
            int row = i / ROWU;            // 0..3
            int hl  = row & 1;
            int wp  = (row >> 1) ? 29 : 0;
            xu[(hl * WPD + wp) * ROWU + (i % ROWU)] = 0u;
        }
    }

    // stage x -> xt[hl][1+w][ci]: thread handles ci-pair (2cig, 2cig+1) so LDS
    // writes are packed u32 (two bf16, ci-adjacent). 7 pairs/thread.
#pragma unroll
    for (int p = 0; p < 7; ++p) {
        int q   = tid + p * NTHR;          // 0..895
        int w4  = q % 7;
        int r   = q / 7;                   // 0..127
        int hl  = r & 1;
        int ci0 = (r >> 1) * 2;            // even ci
        const float* base = xb + ((size_t)ci0 * HH + (h0 + hl)) * WW + w4 * 4;
        float4 v0 = *(const float4*)(base);
        float4 v1 = *(const float4*)(base + HH * WW);
        int wp = 1 + w4 * 4;
        *(unsigned int*)&xt[hl][wp + 0][ci0] = pack_bf2(v0.x, v1.x);
        *(unsigned int*)&xt[hl][wp + 1][ci0] = pack_bf2(v0.y, v1.y);
        *(unsigned int*)&xt[hl][wp + 2][ci0] = pack_bf2(v0.z, v1.z);
        *(unsigned int*)&xt[hl][wp + 3][ci0] = pack_bf2(v0.w, v1.w);
    }

    __syncthreads();

    const int lane = tid & 63;
    const int hl   = tid >> 6;            // wave id = local h row
    const int n    = lane & 31;           // output w (valid < 28)
    const int half = lane >> 5;
    f32x16 acc = {0,0,0,0,0,0,0,0,0,0,0,0,0,0,0,0};

    // K-loop: 3 batches (= kernel tap kk) of 8 MFMA steps
#pragma unroll
    for (int kk = 0; kk < 3; ++kk) {
        short8 afr[8];
#pragma unroll
        for (int u = 0; u < 8; ++u)
            afr[u] = *(const short8*)(wf + (size_t)((kk * 8 + u) * 64 + lane) * 8);
#pragma unroll
        for (int u = 0; u < 8; ++u) {
            short8 bfr = *(const short8*)&xt[hl][n + kk][u * 16 + half * 8];
            acc = __builtin_amdgcn_mfma_f32_32x32x16_bf16(
                __builtin_bit_cast(bf16x8, afr[u]),
                __builtin_bit_cast(bf16x8, bfr), acc, 0, 0, 0);
        }
    }

    // epilogue: roll(+1); pad columns n>=28 dropped
    if (n < WW) {
        const int hout = (h0 + hl + 1) % HH;
#pragma unroll
        for (int r = 0; r < 16; ++r) {
            int co = (r & 3) + 8 * (r >> 2) + 4 * half;
            out[(((size_t)b * COUT + co) * HH + hout) * WW + n] = acc[r];
        }
    }
}

extern "C" void kernel_launch(void* const* d_in, const int* in_sizes, int n_in,
                              void* d_out, int out_size, void* d_ws, size_t ws_size,
                              hipStream_t stream) {
    const float* x  = (const float*)d_in[0];
    const float* wt = (const float*)d_in[1];
    float* out = (float*)d_out;
    unsigned short* wf = (unsigned short*)d_ws;    // 24,576 B of scratch

    build_wfrag<<<48, 256, 0, stream>>>(wt, wf);
    dim3 grid(HH / HROWS, 128);                    // 14 x 128 = 1792 blocks, 7/CU
    conv_mfma<<<grid, NTHR, 0, stream>>>(x, wf, out);
}